// Round 4
// baseline (55632.574 us; speedup 1.0000x reference)
//
#include <hip/hip_runtime.h>
#include <stdint.h>

// (B,S,V,H,O) = (64,1024,32000,1024,128). f32 inputs, f32 output.
// Persistent-LSTM: 256 WGs x 512 thr, 1 WG/CU (forced by 149.5 KB LDS).
// WG = (bh in 0..1: 32 batches) x (cb in 0..127: 8 channels -> 32 gate rows).
// W_ih|W_hh slice staged to LDS once (bf16, MFMA B-frag order). Per step:
//   R: gates_h = h[s] . W_hh^T   (8 waves x 16 mfma_f32_16x16x32_bf16)
//   epilogue: gates = R + gx[s] + bias -> c,h ; h published agent-scope
//   arrive (monotonic device barrier), X: gx[s+1] = xe[s+1] . W_ih^T
//   spin until all 256 WGs arrived, acquire fence.
// Monotonic barrier + double-buffered h is race-free: a WG can only enter
// epilogue(s+1) after ALL WGs finished R(s) (spin target 256*(s+1)).
#define BB 64
#define SS 1024
#define HH 1024
#define NWG 256
#define NTHR 512

typedef unsigned short u16;
typedef unsigned int u32;
typedef short bf8 __attribute__((ext_vector_type(8)));
typedef float f32x4 __attribute__((ext_vector_type(4)));

#define WL_BYTES  131072                    // 2 mats x 32 rows x 2048 K bf16
#define RED_BYTES 9216                      // 8 x 16 x 18 f32
#define LDS_TOTAL (WL_BYTES + 2 * RED_BYTES)  // 149504 < 160 KiB -> 1 WG/CU

static __device__ __forceinline__ u16 f2bf(float f) {
    union { float f; uint32_t u; } v; v.f = f;
    return (u16)((v.u + 0x7fffu + ((v.u >> 16) & 1u)) >> 16);  // RNE
}
static __device__ __forceinline__ float bf2f(u16 u) {
    union { uint32_t u; float f; } v; v.u = ((uint32_t)u) << 16; return v.f;
}
static __device__ __forceinline__ bf8 pack8(const float* p) {
    bf8 r;
    #pragma unroll
    for (int e = 0; e < 8; ++e) r[e] = (short)f2bf(p[e]);
    return r;
}

// Pre-pass: h0 f32 -> hbuf[0] bf16; zero the barrier counter.
__global__ __launch_bounds__(256) void init_h0(
    const float* __restrict__ h0, u16* __restrict__ hbuf0, u32* __restrict__ bar)
{
    int i = blockIdx.x * 256 + threadIdx.x;
    if (i < BB * HH) hbuf0[i] = f2bf(h0[i]);
    if (i == 0) *bar = 0u;
}

__global__ __launch_bounds__(NTHR, 1) void lstm_persist(
    const int*   __restrict__ x,     // [B,S]
    const float* __restrict__ emb,   // [V,H]
    const float* __restrict__ Wih,   // [4H,H]
    const float* __restrict__ Whh,   // [4H,H]
    const float* __restrict__ bih,   // [4H]
    const float* __restrict__ bhh,   // [4H]
    const float* __restrict__ c0,    // [B,H]
    u16*         __restrict__ hbuf,  // ws: 2 x [B,H] bf16 (hbuf[0] = h0)
    u32*         __restrict__ bar)   // ws: barrier counter (zeroed)
{
    extern __shared__ char smem[];
    u16* WL = (u16*)smem;  // unit u = ((mat*2+nh)*32+kb)*64 + lane, elems u*8+e:
                           //   holds W[mat][row(nh, lane&15)][kb*32 + (lane>>4)*8 + e]
    float (*red)[16][18] = (float (*)[16][18])(smem + WL_BYTES);
    float (*gxr)[16][18] = (float (*)[16][18])(smem + WL_BYTES + RED_BYTES);

    const int tid  = threadIdx.x;
    const int wv   = tid >> 6;
    const int lane = tid & 63;
    const int n16  = lane & 15;
    const int quad = lane >> 4;
    const int bh   = blockIdx.x >> 7;   // batch half
    const int cb   = blockIdx.x & 127;  // channel block (8 channels)

    // ---- one-time: stage W slice into LDS (f32 -> bf16, B-frag order) ----
    for (int u = tid; u < 8192; u += NTHR) {
        int ln  = u & 63;
        int kb  = (u >> 6) & 31;
        int nh  = (u >> 11) & 1;
        int mat = u >> 12;
        int rl  = nh * 16 + (ln & 15);      // local row 0..31
        int q   = rl >> 3, j = rl & 7;
        const float* src = (mat ? Whh : Wih)
                         + (size_t)(q * HH + cb * 8 + j) * HH + kb * 32 + (ln >> 4) * 8;
        u16* dst = WL + (size_t)u * 8;
        #pragma unroll
        for (int e = 0; e < 8; ++e) dst[e] = f2bf(src[e]);
    }

    // ---- epilogue-thread constants (threads 0..255 own one (b,ch)) ----
    float bias[4] = {0.f, 0.f, 0.f, 0.f};
    float creg = 0.f;
    int eb = 0, ech = 0;
    if (tid < 256) {
        int bl = tid >> 3, j = tid & 7;
        eb  = bh * 32 + bl;
        ech = cb * 8 + j;
        #pragma unroll
        for (int q = 0; q < 4; ++q) bias[q] = bih[q * HH + ech] + bhh[q * HH + ech];
    }

    // wave role: mh = m-half (batch), nh = n-half (rows), kh = K-half
    const int mh = (wv >> 2) & 1, nh = (wv >> 1) & 1, kh = wv & 1;
    const int ab = bh * 32 + mh * 16 + n16;                 // A batch row (m = lane&15)
    const u16* WLr = WL + ((size_t)((2 + nh) * 32 + kh * 16) * 512) + lane * 8;  // Whh
    const u16* WLx = WL + ((size_t)(nh * 32 + kh * 16) * 512) + lane * 8;        // Wih

    __syncthreads();

    // X-phase: gx[s1] partials -> gxr. A = emb[x[b,s1]] (f32, converted).
    auto xphase = [&](int s1) {
        int xr = x[(size_t)ab * SS + s1];
        const float* ep = emb + (size_t)xr * HH + kh * 512 + quad * 8;
        f32x4 acc = {0.f, 0.f, 0.f, 0.f};
        #pragma unroll
        for (int t = 0; t < 16; ++t) {
            bf8 av = pack8(ep + t * 32);
            bf8 bv = *(const bf8*)(WLx + t * 512);
            acc = __builtin_amdgcn_mfma_f32_16x16x32_bf16(av, bv, acc, 0, 0, 0);
        }
        #pragma unroll
        for (int r = 0; r < 4; ++r) gxr[wv][quad * 4 + r][n16] = acc[r];
    };

    xphase(0);  // gx for step 0 (consumed after sync1 of s=0)

    for (int s = 0; s < SS; ++s) {
        // ---- R-phase: gates_h partials -> red ----
        {
            const u16* hp = hbuf + (size_t)(s & 1) * BB * HH
                          + (size_t)ab * HH + kh * 512 + quad * 8;
            f32x4 acc = {0.f, 0.f, 0.f, 0.f};
            #pragma unroll
            for (int t = 0; t < 16; ++t) {
                bf8 av = *(const bf8*)(hp + t * 32);
                bf8 bv = *(const bf8*)(WLr + t * 512);
                acc = __builtin_amdgcn_mfma_f32_16x16x32_bf16(av, bv, acc, 0, 0, 0);
            }
            #pragma unroll
            for (int r = 0; r < 4; ++r) red[wv][quad * 4 + r][n16] = acc[r];
        }
        __syncthreads();  // sync1: red + gxr(s) ready

        // ---- epilogue: gates -> c,h ; publish h (agent scope) ----
        if (tid < 256) {
            int m   = (tid >> 3) & 15;
            int mhe = tid >> 7;
            int j   = tid & 7;
            float g[4];
            #pragma unroll
            for (int q = 0; q < 4; ++q) {
                int nhe = q >> 1, nn = (q & 1) * 8 + j;
                int w0  = mhe * 4 + nhe * 2;
                g[q] = red[w0][m][nn] + red[w0 + 1][m][nn]
                     + gxr[w0][m][nn] + gxr[w0 + 1][m][nn] + bias[q];
            }
            float ig = 1.f / (1.f + __expf(-g[0]));
            float fg = 1.f / (1.f + __expf(-g[1]));
            float gv = tanhf(g[2]);
            float og = 1.f / (1.f + __expf(-g[3]));
            float cp = (s == 0) ? c0[(size_t)eb * HH + ech] : creg;
            float cn = fg * cp + ig * gv;
            creg = cn;
            u32 hv = f2bf(og * tanhf(cn));
            u32 pv = (u32)__shfl_xor((int)hv, 1);   // partner channel (same wave)
            if ((tid & 1) == 0) {
                u16* hd = hbuf + (size_t)((s + 1) & 1) * BB * HH + (size_t)eb * HH + ech;
                __hip_atomic_store((u32*)hd, hv | (pv << 16),
                                   __ATOMIC_RELAXED, __HIP_MEMORY_SCOPE_AGENT);
            }
        }
        __syncthreads();  // sync2: gxr consumed; h stores drained (vmcnt0 at barrier)

        if (tid == 0) {
            __threadfence();  // release: make h visible across XCDs
            __hip_atomic_fetch_add(bar, 1u, __ATOMIC_RELEASE, __HIP_MEMORY_SCOPE_AGENT);
        }

        if (s + 1 < SS) xphase(s + 1);  // overlap emb gather with barrier wait

        if (tid == 0) {
            u32 tgt = (u32)(s + 1) * NWG;
            while (__hip_atomic_load(bar, __ATOMIC_RELAXED, __HIP_MEMORY_SCOPE_AGENT) < tgt)
                __builtin_amdgcn_s_sleep(1);
        }
        __syncthreads();  // sync3: all waves held until barrier passed
        __threadfence();  // acquire: invalidate stale h lines before next R
    }
}

// out[b][o] = h_last[b] . fc_W[o] + fc_b[o]; f32 out. h_last = hbuf parity 0.
__global__ __launch_bounds__(128) void fc_kernel(
    const u16*   __restrict__ h,
    const float* __restrict__ fcW,
    const float* __restrict__ fcb,
    float*       __restrict__ out)
{
    int b = blockIdx.x;
    int o = threadIdx.x;
    const u16*   hp = h + (size_t)b * HH;
    const float* wp = fcW + (size_t)o * HH;
    float acc = 0.f;
    for (int k = 0; k < HH; k += 8) {
        bf8 hv = *(const bf8*)(hp + k);
        #pragma unroll
        for (int e = 0; e < 8; ++e)
            acc += bf2f((u16)hv[e]) * wp[k + e];
    }
    out[(size_t)b * 128 + o] = acc + fcb[o];
}

extern "C" void kernel_launch(void* const* d_in, const int* in_sizes, int n_in,
                              void* d_out, int out_size, void* d_ws, size_t ws_size,
                              hipStream_t stream) {
    const int*   x   = (const int*)d_in[0];
    const float* emb = (const float*)d_in[1];
    const float* Wih = (const float*)d_in[2];
    const float* Whh = (const float*)d_in[3];
    const float* bih = (const float*)d_in[4];
    const float* bhh = (const float*)d_in[5];
    const float* fcW = (const float*)d_in[6];
    const float* fcb = (const float*)d_in[7];
    const float* h0  = (const float*)d_in[8];
    const float* c0  = (const float*)d_in[9];

    // ws: hbuf 2 x [B,H] bf16 (256 KB) | bar u32
    u16* hbuf = (u16*)d_ws;
    u32* bar  = (u32*)((char*)d_ws + 2 * (size_t)BB * HH * sizeof(u16));

    static bool attr_set = false;  // host-side only; does not affect GPU work
    if (!attr_set) {
        hipFuncSetAttribute((const void*)lstm_persist,
                            hipFuncAttributeMaxDynamicSharedMemorySize, LDS_TOTAL);
        attr_set = true;
    }

    init_h0<<<256, 256, 0, stream>>>(h0, hbuf, bar);
    lstm_persist<<<NWG, NTHR, LDS_TOTAL, stream>>>(x, emb, Wih, Whh, bih, bhh,
                                                   c0, hbuf, bar);
    fc_kernel<<<BB, 128, 0, stream>>>(hbuf, fcW, fcb, (float*)d_out);
}

// Round 5
// 11262.052 us; speedup vs baseline: 4.9398x; 4.9398x over previous
//
#include <hip/hip_runtime.h>
#include <stdint.h>

// (B,S,V,H,O) = (64,1024,32000,1024,128). f32 inputs, f32 output.
// Persistent-LSTM v2: 256 WGs x 512 thr, 1 WG/CU (LDS 145 KB).
// WG = (bh: 32 batches) x (cb: 8 channels -> 32 gate rows, i/f/g/o co-owned).
// Per step:  R: gates = gx(regs) + h[s].W_hh^T  (8 waves, role (mh,kh), both nh)
//            epilogue -> c (regs), h published sc1 (L2-bypass, LLC-coherent)
//            arrive (per-half 8-way split barrier, release-only fence)
//            X: gx(s+1) = xe(s+1).W_ih^T into regs  (overlaps barrier wait)
//            spin (relaxed polls, NO acquire-invalidate: h reads bypass L2,
//                  emb/x are read-only -> no stale copies can exist)
#define BB 64
#define SS 1024
#define HH 1024
#define NWG 256
#define NTHR 512

typedef unsigned short u16;
typedef unsigned int u32;
typedef unsigned long long u64;
typedef short bf8 __attribute__((ext_vector_type(8)));
typedef float f32x4 __attribute__((ext_vector_type(4)));

#define WL_BYTES  131072                     // 2 mats x 32 rows x 2048 K bf16
#define RED_BYTES (16 * 16 * 17 * 4)         // 16 partial tiles, padded
#define LDS_TOTAL (WL_BYTES + RED_BYTES)     // 148480 < 160 KiB -> 1 WG/CU

static __device__ __forceinline__ u16 f2bf(float f) {
    union { float f; uint32_t u; } v; v.f = f;
    return (u16)((v.u + 0x7fffu + ((v.u >> 16) & 1u)) >> 16);  // RNE
}
static __device__ __forceinline__ float bf2f(u16 u) {
    union { uint32_t u; float f; } v; v.u = ((uint32_t)u) << 16; return v.f;
}
static __device__ __forceinline__ bf8 pack8(const float* p) {
    bf8 r;
    #pragma unroll
    for (int e = 0; e < 8; ++e) r[e] = (short)f2bf(p[e]);
    return r;
}

// h0 f32 -> hbuf parity 0 (bf16); zero the barrier counter region.
__global__ __launch_bounds__(256) void init_misc(
    const float* __restrict__ h0, u16* __restrict__ hbuf0, u32* __restrict__ ctr)
{
    int i = blockIdx.x * 256 + threadIdx.x;
    if (i < BB * HH) hbuf0[i] = f2bf(h0[i]);
    if (i < 512) ctr[i] = 0u;   // 16 counters, 128 B apart
}

__global__ __launch_bounds__(NTHR, 1) void lstm_persist(
    const int*   __restrict__ x,     // [B,S]
    const float* __restrict__ emb,   // [V,H]
    const float* __restrict__ Wih,   // [4H,H]
    const float* __restrict__ Whh,   // [4H,H]
    const float* __restrict__ bih,   // [4H]
    const float* __restrict__ bhh,   // [4H]
    const float* __restrict__ c0,    // [B,H]
    u16*         __restrict__ hbuf,  // ws: 2 x [B,H] bf16 (parity 0 = h0)
    u32*         __restrict__ ctr)   // ws: 16 counters, stride 32 u32
{
    extern __shared__ char smem[];
    u16* WL = (u16*)smem;            // chunk ((mat*2+nh)*32+kb)*512 + lane*8
    float (*red)[16][17] = (float (*)[16][17])(smem + WL_BYTES);

    const int tid  = threadIdx.x;
    const int wv   = tid >> 6;
    const int lane = tid & 63;
    const int n16  = lane & 15;
    const int quad = lane >> 4;
    const int bh   = blockIdx.x >> 7;   // batch half
    const int cb   = blockIdx.x & 127;  // channel block (8 channels)

    // ---- one-time: stage W slice into LDS (f32 -> bf16, B-frag order) ----
    for (int u = tid; u < 8192; u += NTHR) {
        int ln  = u & 63;
        int kb  = (u >> 6) & 31;
        int nh  = (u >> 11) & 1;
        int mat = u >> 12;
        int rl  = nh * 16 + (ln & 15);
        int q   = rl >> 3, j = rl & 7;
        const float* src = (mat ? Whh : Wih)
                         + (size_t)(q * HH + cb * 8 + j) * HH + kb * 32 + (ln >> 4) * 8;
        u16* dst = WL + (size_t)u * 8;
        #pragma unroll
        for (int e = 0; e < 8; ++e) dst[e] = f2bf(src[e]);
    }

    // ---- epilogue-thread constants (tid<256 owns one (b,ch)) ----
    float bias[4] = {0.f, 0.f, 0.f, 0.f};
    float creg = 0.f;
    int eb = 0, ech = 0;
    if (tid < 256) {
        int mhe = tid >> 7, m = (tid >> 3) & 15, j = tid & 7;
        eb  = bh * 32 + mhe * 16 + m;
        ech = cb * 8 + j;
        #pragma unroll
        for (int q = 0; q < 4; ++q) bias[q] = bih[q * HH + ech] + bhh[q * HH + ech];
    }

    // wave role: mh (batch 16-half), kh (K quarter of 1024); both nh in regs
    const int mh = wv >> 2, kh = wv & 3;
    const int ab = bh * 32 + mh * 16 + n16;   // A batch row (m = lane&15)
    const u16* WLx0 = WL + ((size_t)(0 * 32 + kh * 8) * 512) + lane * 8;  // Wih nh=0
    const u16* WLx1 = WL + ((size_t)(1 * 32 + kh * 8) * 512) + lane * 8;  // Wih nh=1
    const u16* WLr0 = WL + ((size_t)(2 * 32 + kh * 8) * 512) + lane * 8;  // Whh nh=0
    const u16* WLr1 = WL + ((size_t)(3 * 32 + kh * 8) * 512) + lane * 8;  // Whh nh=1

    __syncthreads();  // WL ready

    u32* myctr  = ctr + (size_t)(bh * 8 + (cb & 7)) * 32;

    f32x4 accx0, accx1;   // gx partials, carried in regs across the barrier
    auto xphase = [&](int s1) {
        int xr = x[(size_t)ab * SS + s1];
        const float* ep = emb + (size_t)xr * HH + kh * 256 + quad * 8;
        f32x4 a0 = {0.f, 0.f, 0.f, 0.f}, a1 = {0.f, 0.f, 0.f, 0.f};
        #pragma unroll
        for (int t = 0; t < 8; ++t) {
            bf8 av = pack8(ep + t * 32);
            bf8 b0 = *(const bf8*)(WLx0 + t * 512);
            bf8 b1 = *(const bf8*)(WLx1 + t * 512);
            a0 = __builtin_amdgcn_mfma_f32_16x16x32_bf16(av, b0, a0, 0, 0, 0);
            a1 = __builtin_amdgcn_mfma_f32_16x16x32_bf16(av, b1, a1, 0, 0, 0);
        }
        accx0 = a0; accx1 = a1;
    };

    xphase(0);

    for (int s = 0; s < SS; ++s) {
        // ---- R-phase: acc = gx + h[s].W_hh^T ; h via L2-bypassing loads ----
        {
            const u16* hp = hbuf + (size_t)(s & 1) * BB * HH
                          + (size_t)ab * HH + kh * 256 + quad * 8;
            f32x4 a0 = accx0, a1 = accx1;
            #pragma unroll
            for (int t = 0; t < 8; ++t) {
                union { u64 q[2]; bf8 v; } av;
                av.q[0] = __hip_atomic_load((const u64*)(hp + t * 32),
                                            __ATOMIC_RELAXED, __HIP_MEMORY_SCOPE_AGENT);
                av.q[1] = __hip_atomic_load((const u64*)(hp + t * 32 + 4),
                                            __ATOMIC_RELAXED, __HIP_MEMORY_SCOPE_AGENT);
                bf8 b0 = *(const bf8*)(WLr0 + t * 512);
                bf8 b1 = *(const bf8*)(WLr1 + t * 512);
                a0 = __builtin_amdgcn_mfma_f32_16x16x32_bf16(av.v, b0, a0, 0, 0, 0);
                a1 = __builtin_amdgcn_mfma_f32_16x16x32_bf16(av.v, b1, a1, 0, 0, 0);
            }
            const int w2 = wv * 2;     // 16 partial tiles: (mh*4+kh)*2 + nh
            #pragma unroll
            for (int r = 0; r < 4; ++r) {   // C/D: col(n)=lane&15, row(m)=quad*4+r
                red[w2 + 0][quad * 4 + r][n16] = a0[r];
                red[w2 + 1][quad * 4 + r][n16] = a1[r];
            }
        }
        __syncthreads();  // sync1: red ready

        // ---- epilogue: gates -> c,h ; publish h sc1 (LLC) ----
        if (tid < 256) {
            const int mhe = tid >> 7, m = (tid >> 3) & 15, j = tid & 7;
            float g[4];
            #pragma unroll
            for (int q = 0; q < 4; ++q) {
                const int nh = q >> 1, nn = (q & 1) * 8 + j;
                float acc = bias[q];
                #pragma unroll
                for (int k = 0; k < 4; ++k)
                    acc += red[(mhe * 4 + k) * 2 + nh][m][nn];
                g[q] = acc;
            }
            float ig = 1.f / (1.f + __expf(-g[0]));
            float fg = 1.f / (1.f + __expf(-g[1]));
            float gv = tanhf(g[2]);
            float og = 1.f / (1.f + __expf(-g[3]));
            float cp = (s == 0) ? c0[(size_t)eb * HH + ech] : creg;
            float cn = fg * cp + ig * gv;
            creg = cn;
            u32 hv = f2bf(og * tanhf(cn));
            u32 pv = (u32)__shfl_xor((int)hv, 1);   // partner channel (ech^1)
            if ((tid & 1) == 0) {
                u16* hd = hbuf + (size_t)((s + 1) & 1) * BB * HH + (size_t)eb * HH + ech;
                __hip_atomic_store((u32*)hd, hv | (pv << 16),
                                   __ATOMIC_RELAXED, __HIP_MEMORY_SCOPE_AGENT);
            }
        }
        __syncthreads();  // sync2: h stores drained (vmcnt(0) at barrier)

        if (s + 1 < SS) {
            if (tid == 0) {   // release (wbl2, NO invalidate) then arrive
                __builtin_amdgcn_fence(__ATOMIC_RELEASE, "agent");
                __hip_atomic_fetch_add(myctr, 1u, __ATOMIC_RELAXED,
                                       __HIP_MEMORY_SCOPE_AGENT);
            }
            xphase(s + 1);    // overlap emb gather + gx MFMA with barrier wait
            if (tid < 8) {    // per-half split barrier: 8 counters x 16 arrivals
                const u32 tgt = (u32)(s + 1) * 16u;
                u32* pc = ctr + (size_t)(bh * 8 + tid) * 32;
                while (__hip_atomic_load(pc, __ATOMIC_RELAXED,
                                         __HIP_MEMORY_SCOPE_AGENT) < tgt)
                    __builtin_amdgcn_s_sleep(1);
            }
            __syncthreads();  // sync3: all waves held until half-barrier passed
            // no acquire-invalidate: h reads bypass L2; emb/x/c0 are read-only
        }
    }
}

// out[b][o] = h_last[b] . fc_W[o] + fc_b[o]; f32 out. h_last = hbuf parity 0.
__global__ __launch_bounds__(128) void fc_kernel(
    const u16*   __restrict__ h,
    const float* __restrict__ fcW,
    const float* __restrict__ fcb,
    float*       __restrict__ out)
{
    int b = blockIdx.x;
    int o = threadIdx.x;
    const u16*   hp = h + (size_t)b * HH;
    const float* wp = fcW + (size_t)o * HH;
    float acc = 0.f;
    for (int k = 0; k < HH; k += 8) {
        bf8 hv = *(const bf8*)(hp + k);
        #pragma unroll
        for (int e = 0; e < 8; ++e)
            acc += bf2f((u16)hv[e]) * wp[k + e];
    }
    out[(size_t)b * 128 + o] = acc + fcb[o];
}

extern "C" void kernel_launch(void* const* d_in, const int* in_sizes, int n_in,
                              void* d_out, int out_size, void* d_ws, size_t ws_size,
                              hipStream_t stream) {
    const int*   x   = (const int*)d_in[0];
    const float* emb = (const float*)d_in[1];
    const float* Wih = (const float*)d_in[2];
    const float* Whh = (const float*)d_in[3];
    const float* bih = (const float*)d_in[4];
    const float* bhh = (const float*)d_in[5];
    const float* fcW = (const float*)d_in[6];
    const float* fcb = (const float*)d_in[7];
    const float* h0  = (const float*)d_in[8];
    const float* c0  = (const float*)d_in[9];

    // ws: hbuf 2 x [B,H] bf16 (256 KB) | ctr region 2 KB
    u16* hbuf = (u16*)d_ws;
    u32* ctr  = (u32*)((char*)d_ws + 2 * (size_t)BB * HH * sizeof(u16));

    hipFuncSetAttribute((const void*)lstm_persist,
                        hipFuncAttributeMaxDynamicSharedMemorySize, LDS_TOTAL);

    init_misc<<<256, 256, 0, stream>>>(h0, hbuf, ctr);
    lstm_persist<<<NWG, NTHR, LDS_TOTAL, stream>>>(x, emb, Wih, Whh, bih, bhh,
                                                   c0, hbuf, ctr);
    fc_kernel<<<BB, 128, 0, stream>>>(hbuf, fcW, fcb, (float*)d_out);
}

// Round 6
// 9161.911 us; speedup vs baseline: 6.0722x; 1.2292x over previous
//
#include <hip/hip_runtime.h>
#include <stdint.h>

// (B,S,V,H,O) = (64,1024,32000,1024,128). f32 inputs, f32 output.
// Persistent-LSTM v3: 256 WGs x 512 thr, 1 WG/CU (LDS 145 KB).
// WG = (bh: 32 batches) x (cb: 8 channels -> 32 gate rows i/f/g/o co-owned).
// Per step: prefetch emb(s+1) into regs (latency hidden behind R+epilogue);
//   R: gates = gx(regs) + h[s].W_hh^T (h via L2-bypass atomic loads, batched);
//   epilogue -> c (regs), h published sc1 (write-through to LLC; proven by R5);
//   arrive (relaxed RMW; ordering = sync2's vmcnt(0) drain — NO wbl2 fence);
//   X: gx(s+1) MFMA from prefetched regs; spin relaxed; NO acquire-invalidate.
#define BB 64
#define SS 1024
#define HH 1024
#define NWG 256
#define NTHR 512

typedef unsigned short u16;
typedef unsigned int u32;
typedef unsigned long long u64;
typedef short bf8 __attribute__((ext_vector_type(8)));
typedef float f32x4 __attribute__((ext_vector_type(4)));

#define WL_BYTES  131072                     // 2 mats x 32 rows x 2048 K bf16
#define RED_BYTES (16 * 16 * 17 * 4)         // 16 partial tiles, padded
#define LDS_TOTAL (WL_BYTES + RED_BYTES)     // 148480 < 160 KiB -> 1 WG/CU

static __device__ __forceinline__ u16 f2bf(float f) {
    union { float f; uint32_t u; } v; v.f = f;
    return (u16)((v.u + 0x7fffu + ((v.u >> 16) & 1u)) >> 16);  // RNE
}
static __device__ __forceinline__ float bf2f(u16 u) {
    union { uint32_t u; float f; } v; v.u = ((uint32_t)u) << 16; return v.f;
}
static __device__ __forceinline__ float fsig(float x) {        // v_exp + v_rcp
    return __builtin_amdgcn_rcpf(1.f + __expf(-x));
}
static __device__ __forceinline__ float ftanh(float x) {
    return 1.f - 2.f * __builtin_amdgcn_rcpf(1.f + __expf(2.f * x));
}
static __device__ __forceinline__ bf8 pack2(f32x4 a, f32x4 b) {
    bf8 r;
    #pragma unroll
    for (int e = 0; e < 4; ++e) { r[e] = (short)f2bf(a[e]); r[4 + e] = (short)f2bf(b[e]); }
    return r;
}

// h0 f32 -> hbuf parity 0 (bf16); zero the barrier counters.
__global__ __launch_bounds__(256) void init_misc(
    const float* __restrict__ h0, u16* __restrict__ hbuf0, u32* __restrict__ ctr)
{
    int i = blockIdx.x * 256 + threadIdx.x;
    if (i < BB * HH) hbuf0[i] = f2bf(h0[i]);
    if (i < 512) ctr[i] = 0u;   // 16 counters, 128 B apart
}

__global__ __launch_bounds__(NTHR, 1) void lstm_persist(
    const int*   __restrict__ x,     // [B,S]
    const float* __restrict__ emb,   // [V,H]
    const float* __restrict__ Wih,   // [4H,H]
    const float* __restrict__ Whh,   // [4H,H]
    const float* __restrict__ bih,   // [4H]
    const float* __restrict__ bhh,   // [4H]
    const float* __restrict__ c0,    // [B,H]
    u16*         __restrict__ hbuf,  // ws: 2 x [B,H] bf16 (parity 0 = h0)
    u32*         __restrict__ ctr)   // ws: 16 counters, stride 32 u32
{
    extern __shared__ char smem[];
    u16* WL = (u16*)smem;            // chunk ((mat*2+nh)*32+kb)*512 + lane*8
    float (*red)[16][17] = (float (*)[16][17])(smem + WL_BYTES);

    const int tid  = threadIdx.x;
    const int wv   = tid >> 6;
    const int lane = tid & 63;
    const int n16  = lane & 15;
    const int quad = lane >> 4;
    const int bh   = blockIdx.x >> 7;   // batch half
    const int cb   = blockIdx.x & 127;  // channel block (8 channels)

    // ---- one-time: stage W slice into LDS (f32 -> bf16, B-frag order) ----
    for (int u = tid; u < 8192; u += NTHR) {
        int ln  = u & 63;
        int kb  = (u >> 6) & 31;
        int nh  = (u >> 11) & 1;
        int mat = u >> 12;
        int rl  = nh * 16 + (ln & 15);
        int q   = rl >> 3, j = rl & 7;
        const float* src = (mat ? Whh : Wih)
                         + (size_t)(q * HH + cb * 8 + j) * HH + kb * 32 + (ln >> 4) * 8;
        u16* dst = WL + (size_t)u * 8;
        #pragma unroll
        for (int e = 0; e < 8; ++e) dst[e] = f2bf(src[e]);
    }

    // ---- epilogue-thread constants (tid<256 owns one (b,ch)) ----
    float bias[4] = {0.f, 0.f, 0.f, 0.f};
    float creg = 0.f;
    int eb = 0, ech = 0;
    if (tid < 256) {
        int mhe = tid >> 7, m = (tid >> 3) & 15, j = tid & 7;
        eb  = bh * 32 + mhe * 16 + m;
        ech = cb * 8 + j;
        #pragma unroll
        for (int q = 0; q < 4; ++q) bias[q] = bih[q * HH + ech] + bhh[q * HH + ech];
    }

    // wave role: mh (batch 16-half), kh (K quarter of 1024); both nh per wave
    const int mh = wv >> 2, kh = wv & 3;
    const int ab = bh * 32 + mh * 16 + n16;   // A batch row (m = lane&15)
    const u16* WLx0 = WL + ((size_t)(0 * 32 + kh * 8) * 512) + lane * 8;  // Wih nh=0
    const u16* WLx1 = WL + ((size_t)(1 * 32 + kh * 8) * 512) + lane * 8;  // Wih nh=1
    const u16* WLr0 = WL + ((size_t)(2 * 32 + kh * 8) * 512) + lane * 8;  // Whh nh=0
    const u16* WLr1 = WL + ((size_t)(3 * 32 + kh * 8) * 512) + lane * 8;  // Whh nh=1

    __syncthreads();  // WL ready

    u32* myctr = ctr + (size_t)(bh * 8 + (cb & 7)) * 32;

    // gx partials for the CURRENT step, carried in regs across the barrier.
    f32x4 accx0, accx1;
    {   // step 0's X-phase (pre-loop; latency not critical here)
        int xr = x[(size_t)ab * SS + 0];
        const float* ep = emb + (size_t)xr * HH + kh * 256 + quad * 8;
        f32x4 a0 = {0.f, 0.f, 0.f, 0.f}, a1 = {0.f, 0.f, 0.f, 0.f};
        #pragma unroll
        for (int t = 0; t < 8; ++t) {
            bf8 av = pack2(*(const f32x4*)(ep + t * 32), *(const f32x4*)(ep + t * 32 + 4));
            bf8 b0 = *(const bf8*)(WLx0 + t * 512);
            bf8 b1 = *(const bf8*)(WLx1 + t * 512);
            a0 = __builtin_amdgcn_mfma_f32_16x16x32_bf16(av, b0, a0, 0, 0, 0);
            a1 = __builtin_amdgcn_mfma_f32_16x16x32_bf16(av, b1, a1, 0, 0, 0);
        }
        accx0 = a0; accx1 = a1;
    }

    for (int s = 0; s < SS; ++s) {
        const bool more = (s + 1 < SS);

        // ---- prefetch emb(s+1) into registers (hidden behind R + epilogue) ----
        f32x4 pf[16];
        if (more) {
            int xr = x[(size_t)ab * SS + (s + 1)];
            const float* ep = emb + (size_t)xr * HH + kh * 256 + quad * 8;
            #pragma unroll
            for (int t = 0; t < 8; ++t) {
                pf[2 * t]     = *(const f32x4*)(ep + t * 32);
                pf[2 * t + 1] = *(const f32x4*)(ep + t * 32 + 4);
            }
        }

        // ---- R-phase: acc = gx + h[s].W_hh^T ; batched L2-bypass h loads ----
        {
            const u16* hp = hbuf + (size_t)(s & 1) * BB * HH
                          + (size_t)ab * HH + kh * 256 + quad * 8;
            u64 hq[16];
            #pragma unroll
            for (int t = 0; t < 8; ++t) {   // issue all 16 loads, one latency
                hq[2 * t]     = __hip_atomic_load((const u64*)(hp + t * 32),
                                    __ATOMIC_RELAXED, __HIP_MEMORY_SCOPE_AGENT);
                hq[2 * t + 1] = __hip_atomic_load((const u64*)(hp + t * 32 + 4),
                                    __ATOMIC_RELAXED, __HIP_MEMORY_SCOPE_AGENT);
            }
            f32x4 a0 = accx0, a1 = accx1;
            #pragma unroll
            for (int t = 0; t < 8; ++t) {
                union { u64 q[2]; bf8 v; } av;
                av.q[0] = hq[2 * t]; av.q[1] = hq[2 * t + 1];
                bf8 b0 = *(const bf8*)(WLr0 + t * 512);
                bf8 b1 = *(const bf8*)(WLr1 + t * 512);
                a0 = __builtin_amdgcn_mfma_f32_16x16x32_bf16(av.v, b0, a0, 0, 0, 0);
                a1 = __builtin_amdgcn_mfma_f32_16x16x32_bf16(av.v, b1, a1, 0, 0, 0);
            }
            const int w2 = wv * 2;     // 16 partial tiles: (mh*4+kh)*2 + nh
            #pragma unroll
            for (int r = 0; r < 4; ++r) {   // C/D: col(n)=lane&15, row(m)=quad*4+r
                red[w2 + 0][quad * 4 + r][n16] = a0[r];
                red[w2 + 1][quad * 4 + r][n16] = a1[r];
            }
        }
        __syncthreads();  // sync1: red ready

        // ---- epilogue: gates -> c,h ; publish h sc1 (write-through to LLC) ----
        if (tid < 256) {
            const int mhe = tid >> 7, m = (tid >> 3) & 15, j = tid & 7;
            float g[4];
            #pragma unroll
            for (int q = 0; q < 4; ++q) {
                const int nh = q >> 1, nn = (q & 1) * 8 + j;
                float acc = bias[q];
                #pragma unroll
                for (int k = 0; k < 4; ++k)
                    acc += red[(mhe * 4 + k) * 2 + nh][m][nn];
                g[q] = acc;
            }
            float ig = fsig(g[0]);
            float fg = fsig(g[1]);
            float gv = ftanh(g[2]);
            float og = fsig(g[3]);
            float cp = (s == 0) ? c0[(size_t)eb * HH + ech] : creg;
            float cn = fg * cp + ig * gv;
            creg = cn;
            u32 hv = f2bf(og * ftanh(cn));
            u32 pv = (u32)__shfl_xor((int)hv, 1);   // partner channel (ech^1)
            if ((tid & 1) == 0) {
                u16* hd = hbuf + (size_t)((s + 1) & 1) * BB * HH + (size_t)eb * HH + ech;
                __hip_atomic_store((u32*)hd, hv | (pv << 16),
                                   __ATOMIC_RELAXED, __HIP_MEMORY_SCOPE_AGENT);
            }
        }
        __syncthreads();  // sync2: ALL waves' h stores drained (vmcnt(0) @ barrier)

        if (more) {
            if (tid == 0) {          // arrive: relaxed RMW; no wbl2 fence
                __threadfence_block();   // belt&braces: own-wave vmcnt drain only
                __hip_atomic_fetch_add(myctr, 1u, __ATOMIC_RELAXED,
                                       __HIP_MEMORY_SCOPE_AGENT);
            }
            // X-phase compute from prefetched regs (VALU+MFMA only)
            {
                f32x4 a0 = {0.f, 0.f, 0.f, 0.f}, a1 = {0.f, 0.f, 0.f, 0.f};
                #pragma unroll
                for (int t = 0; t < 8; ++t) {
                    bf8 av = pack2(pf[2 * t], pf[2 * t + 1]);
                    bf8 b0 = *(const bf8*)(WLx0 + t * 512);
                    bf8 b1 = *(const bf8*)(WLx1 + t * 512);
                    a0 = __builtin_amdgcn_mfma_f32_16x16x32_bf16(av, b0, a0, 0, 0, 0);
                    a1 = __builtin_amdgcn_mfma_f32_16x16x32_bf16(av, b1, a1, 0, 0, 0);
                }
                accx0 = a0; accx1 = a1;
            }
            if (tid < 8) {           // per-half split barrier: 8 ctrs x 16 arrivals
                const u32 tgt = (u32)(s + 1) * 16u;
                u32* pc = ctr + (size_t)(bh * 8 + tid) * 32;
                while (__hip_atomic_load(pc, __ATOMIC_RELAXED,
                                         __HIP_MEMORY_SCOPE_AGENT) < tgt)
                    __builtin_amdgcn_s_sleep(1);
            }
            __syncthreads();  // sync3: all waves held until half-barrier passed
            // no acquire-invalidate: h reads bypass L2; emb/x/c0 are read-only
        }
    }
}

// out[b][o] = h_last[b] . fc_W[o] + fc_b[o]; f32 out. h_last = hbuf parity 0.
__global__ __launch_bounds__(128) void fc_kernel(
    const u16*   __restrict__ h,
    const float* __restrict__ fcW,
    const float* __restrict__ fcb,
    float*       __restrict__ out)
{
    int b = blockIdx.x;
    int o = threadIdx.x;
    const u16*   hp = h + (size_t)b * HH;
    const float* wp = fcW + (size_t)o * HH;
    float acc = 0.f;
    for (int k = 0; k < HH; k += 8) {
        bf8 hv = *(const bf8*)(hp + k);
        #pragma unroll
        for (int e = 0; e < 8; ++e)
            acc += bf2f((u16)hv[e]) * wp[k + e];
    }
    out[(size_t)b * 128 + o] = acc + fcb[o];
}

extern "C" void kernel_launch(void* const* d_in, const int* in_sizes, int n_in,
                              void* d_out, int out_size, void* d_ws, size_t ws_size,
                              hipStream_t stream) {
    const int*   x   = (const int*)d_in[0];
    const float* emb = (const float*)d_in[1];
    const float* Wih = (const float*)d_in[2];
    const float* Whh = (const float*)d_in[3];
    const float* bih = (const float*)d_in[4];
    const float* bhh = (const float*)d_in[5];
    const float* fcW = (const float*)d_in[6];
    const float* fcb = (const float*)d_in[7];
    const float* h0  = (const float*)d_in[8];
    const float* c0  = (const float*)d_in[9];

    // ws: hbuf 2 x [B,H] bf16 (256 KB) | ctr region 2 KB
    u16* hbuf = (u16*)d_ws;
    u32* ctr  = (u32*)((char*)d_ws + 2 * (size_t)BB * HH * sizeof(u16));

    hipFuncSetAttribute((const void*)lstm_persist,
                        hipFuncAttributeMaxDynamicSharedMemorySize, LDS_TOTAL);

    init_misc<<<256, 256, 0, stream>>>(h0, hbuf, ctr);
    lstm_persist<<<NWG, NTHR, LDS_TOTAL, stream>>>(x, emb, Wih, Whh, bih, bhh,
                                                   c0, hbuf, ctr);
    fc_kernel<<<BB, 128, 0, stream>>>(hbuf, fcW, fcb, (float*)d_out);
}